// Round 3
// baseline (86.240 us; speedup 1.0000x reference)
//
#include <hip/hip_runtime.h>

#define BATCH 64
#define NPTS  4096
#define NFRAMES 100
#define BLOCK 256
#define PPT 2                          // points per thread
#define KSPAN (BLOCK * PPT)            // 512
#define NBLK_X (NPTS / KSPAN)          // 8
#define NBLOCKS (BATCH * NBLK_X)       // 512
#define EPS_DIST_F 1e-8f

// R3: single fused kernel. The two-kernel chain (fape_main -> fape_final)
// cost a dependent dispatch + grid-drain in the captured graph; per-iteration
// timing is dominated by the harness's 256 MiB ws poison-fill (40.5 us @ 6.6
// TB/s, measured) plus launch/gap overhead, NOT by this kernel's ALU work
// (~3-5 us model). So: fold the final reduction in via device-scope atomics
// + ticket counter + last-block finalize. ws usage shrinks to 16 bytes
// (num, den, counter), zeroed by a tiny hipMemsetAsync before the kernel.
//
// Math note: reference rotates diff by an orthonormal frame before the norm;
// rotation preserves the 2-norm, so distance = ||(pred_k - true_k) -
// (pred_f - true_f)||. Frame origins are the first NFRAMES points.
__global__ __launch_bounds__(BLOCK) void fape_fused(
    const float* __restrict__ pred,
    const float* __restrict__ truec,
    const float* __restrict__ mask,
    float* __restrict__ ws,            // [0]=num, [1]=den, [2]=ticket (u32)
    float* __restrict__ out)
{
    __shared__ __align__(16) float sfx[NFRAMES];
    __shared__ __align__(16) float sfy[NFRAMES];
    __shared__ __align__(16) float sfz[NFRAMES];

    const int b  = blockIdx.y;
    const int k0 = blockIdx.x * KSPAN + threadIdx.x;
    const int k1 = k0 + BLOCK;

    const float* __restrict__ pb = pred  + (size_t)b * NPTS * 3;
    const float* __restrict__ tb = truec + (size_t)b * NPTS * 3;

    // Issue the point loads FIRST: their HBM latency drains during the
    // staging stores + barrier (compiler waits vmcnt(0) before s_barrier).
    const float p0x = pb[3 * k0 + 0], p0y = pb[3 * k0 + 1], p0z = pb[3 * k0 + 2];
    const float t0x = tb[3 * k0 + 0], t0y = tb[3 * k0 + 1], t0z = tb[3 * k0 + 2];
    const float p1x = pb[3 * k1 + 0], p1y = pb[3 * k1 + 1], p1z = pb[3 * k1 + 2];
    const float t1x = tb[3 * k1 + 0], t1y = tb[3 * k1 + 1], t1z = tb[3 * k1 + 2];

    // Stage frame deltas (origins f = coords[:, :-2] -> first 100 points).
    if (threadIdx.x < NFRAMES) {
        const int t = threadIdx.x;
        sfx[t] = pb[3 * t + 0] - tb[3 * t + 0];
        sfy[t] = pb[3 * t + 1] - tb[3 * t + 1];
        sfz[t] = pb[3 * t + 2] - tb[3 * t + 2];
    }
    __syncthreads();

    const float d0x = p0x - t0x, d0y = p0y - t0y, d0z = p0z - t0z;
    const float d1x = p1x - t1x, d1y = p1y - t1y, d1z = p1z - t1z;

    float acc0 = 0.0f, acc1 = 0.0f;

#define EVAL(DX, DY, DZ, FX, FY, FZ, ACC) do {                                  \
        const float ex_ = (DX) - (FX);                                          \
        const float ey_ = (DY) - (FY);                                          \
        const float ez_ = (DZ) - (FZ);                                          \
        const float s_  = __builtin_fmaf(ex_, ex_,                              \
                          __builtin_fmaf(ey_, ey_,                              \
                          __builtin_fmaf(ez_, ez_, EPS_DIST_F)));               \
        (ACC) += fminf(__builtin_amdgcn_sqrtf(s_), 10.0f);                      \
    } while (0)

#pragma unroll 2
    for (int f = 0; f < NFRAMES; f += 4) {
        const float4 fx = *(const float4*)&sfx[f];
        const float4 fy = *(const float4*)&sfy[f];
        const float4 fz = *(const float4*)&sfz[f];

        EVAL(d0x, d0y, d0z, fx.x, fy.x, fz.x, acc0);
        EVAL(d1x, d1y, d1z, fx.x, fy.x, fz.x, acc1);
        EVAL(d0x, d0y, d0z, fx.y, fy.y, fz.y, acc0);
        EVAL(d1x, d1y, d1z, fx.y, fy.y, fz.y, acc1);
        EVAL(d0x, d0y, d0z, fx.z, fy.z, fz.z, acc0);
        EVAL(d1x, d1y, d1z, fx.z, fy.z, fz.z, acc1);
        EVAL(d0x, d0y, d0z, fx.w, fy.w, fz.w, acc0);
        EVAL(d1x, d1y, d1z, fx.w, fy.w, fz.w, acc1);
    }
#undef EVAL

    const float m0 = mask[(size_t)b * NPTS + k0];
    const float m1 = mask[(size_t)b * NPTS + k1];
    float num = (acc0 * m0 + acc1 * m1) * 0.1f;
    float den = m0 + m1;

    // Wave-64 shuffle reduction.
    for (int off = 32; off > 0; off >>= 1) {
        num += __shfl_down(num, off, 64);
        den += __shfl_down(den, off, 64);
    }

    __shared__ float snum[BLOCK / 64];
    __shared__ float sden[BLOCK / 64];
    const int wave = threadIdx.x >> 6;
    const int lane = threadIdx.x & 63;
    if (lane == 0) { snum[wave] = num; sden[wave] = den; }
    __syncthreads();

    if (threadIdx.x == 0) {
        float n2 = 0.0f, d2 = 0.0f;
#pragma unroll
        for (int w = 0; w < BLOCK / 64; ++w) { n2 += snum[w]; d2 += sden[w]; }

        // Device-scope accumulation (atomicAdd on global is device-scope;
        // safe across non-coherent per-XCD L2s).
        atomicAdd(&ws[0], n2);
        atomicAdd(&ws[1], d2);
        __threadfence();
        unsigned int old = atomicAdd((unsigned int*)&ws[2], 1u);
        if (old == NBLOCKS - 1) {
            // Last block: read accumulators via device-scope RMW (avoids a
            // stale plain-load from a non-coherent local L2).
            const float n = atomicAdd(&ws[0], 0.0f);
            const float d = atomicAdd(&ws[1], 0.0f);
            out[0] = n / (d + EPS_DIST_F);
        }
    }
}

extern "C" void kernel_launch(void* const* d_in, const int* in_sizes, int n_in,
                              void* d_out, int out_size, void* d_ws, size_t ws_size,
                              hipStream_t stream)
{
    const float* pred  = (const float*)d_in[0];
    const float* truec = (const float*)d_in[1];
    const float* mask  = (const float*)d_in[2];
    float* out = (float*)d_out;
    float* ws  = (float*)d_ws;

    // Zero num/den accumulators + ticket counter (16 B, graph-capturable).
    hipMemsetAsync(ws, 0, 16, stream);

    dim3 grid(NBLK_X, BATCH);
    fape_fused<<<grid, BLOCK, 0, stream>>>(pred, truec, mask, ws, out);
}